// Round 3
// baseline (1361.066 us; speedup 1.0000x reference)
//
#include <hip/hip_runtime.h>
#include <hip/hip_bf16.h>
#include <math.h>

typedef unsigned short u16;
typedef unsigned int u32;
typedef __bf16 bf16x8 __attribute__((ext_vector_type(8)));
typedef float f32x4 __attribute__((ext_vector_type(4)));

#define T_TOK 4096
#define HID   1024
#define INTER 4096
#define NEXP  8

// ---------------- workspace layout (bytes) ----------------
#define WS_NEEDED 209978368ull

__device__ __forceinline__ u16 f2bf(float f) {
    u32 u = __builtin_bit_cast(u32, f);
    u += 0x7FFFu + ((u >> 16) & 1u);   // round-to-nearest-even
    return (u16)(u >> 16);
}

// fast exact-enough gelu: tanh approximation, stable rational form.
__device__ __forceinline__ float fast_gelu(float v) {
    float u2 = v * (-1.5957691216f - 0.0713548163f * v * v);  // -2u
    return v / (1.0f + __expf(u2));
}

// ---------------- router: fp32 logits + top-2 lists ----------------
__global__ __launch_bounds__(256) void router_kernel(
    const float* __restrict__ x, const float* __restrict__ gw,
    float* __restrict__ logits, int* __restrict__ counts,
    int* __restrict__ tlist, float* __restrict__ wlist)
{
    const int lane = threadIdx.x & 63, wv = threadIdx.x >> 6;
    const int t = blockIdx.x * 4 + wv;
    const float* xr = x + (size_t)t * HID;
    float a[8] = {0.f,0.f,0.f,0.f,0.f,0.f,0.f,0.f};
    for (int h = lane; h < HID; h += 64) {
        float xv = xr[h];
        const float4* g4 = (const float4*)(gw + h * 8);
        float4 g0 = g4[0], g1 = g4[1];
        a[0] += xv * g0.x; a[1] += xv * g0.y; a[2] += xv * g0.z; a[3] += xv * g0.w;
        a[4] += xv * g1.x; a[5] += xv * g1.y; a[6] += xv * g1.z; a[7] += xv * g1.w;
    }
#pragma unroll
    for (int e = 0; e < 8; e++) {
        float v = a[e];
        for (int o = 32; o > 0; o >>= 1) v += __shfl_down(v, o, 64);
        a[e] = v;
    }
    if (lane == 0) {
#pragma unroll
        for (int e = 0; e < 8; e++) logits[(size_t)t * 8 + e] = a[e];
        int e1 = 0; float b1 = a[0];
        for (int e = 1; e < 8; e++) if (a[e] > b1) { b1 = a[e]; e1 = e; }
        int e2 = -1; float b2 = -1e30f;
        for (int e = 0; e < 8; e++) if (e != e1 && a[e] > b2) { b2 = a[e]; e2 = e; }
        float wa = 1.0f / (1.0f + expf(b2 - b1));
        float wb = 1.0f - wa;
        int p = atomicAdd(&counts[e1], 1);
        tlist[e1 * T_TOK + p] = t; wlist[e1 * T_TOK + p] = wa;
        p = atomicAdd(&counts[e2], 1);
        tlist[e2 * T_TOK + p] = t; wlist[e2 * T_TOK + p] = wb;
    }
}

__global__ void scan_kernel(const int* __restrict__ counts, int* __restrict__ offs)
{
    if (threadIdx.x == 0) {
        int s = 0;
        for (int e = 0; e < 8; e++) { offs[e] = s; s += counts[e]; }
    }
}

// ---------------- fp32 -> bf16 convert (x) ----------------
__global__ __launch_bounds__(256) void convert_x_kernel(
    const float* __restrict__ src, u16* __restrict__ dst)
{
    const int idx = (blockIdx.x * 256 + threadIdx.x) * 8;
    float4 f0 = *(const float4*)(src + idx);
    float4 f1 = *(const float4*)(src + idx + 4);
    uint4 o;
    o.x = (u32)f2bf(f0.x) | ((u32)f2bf(f0.y) << 16);
    o.y = (u32)f2bf(f0.z) | ((u32)f2bf(f0.w) << 16);
    o.z = (u32)f2bf(f1.x) | ((u32)f2bf(f1.y) << 16);
    o.w = (u32)f2bf(f1.z) | ((u32)f2bf(f1.w) << 16);
    *(uint4*)(dst + idx) = o;
}

// ------- transpose + convert: src[E][R][C] f32 -> dst[E][C][R] bf16 -------
__global__ __launch_bounds__(256) void transpose_convert_kernel(
    const float* __restrict__ src, u16* __restrict__ dst, int R, int C)
{
    __shared__ float tl[64][65];   // [c][r], +1 pad
    const int e = blockIdx.z;
    const int c0 = blockIdx.x * 64, r0 = blockIdx.y * 64;
    const float* s = src + (size_t)e * R * C + (size_t)r0 * C + c0;
    const int tid = threadIdx.x;
#pragma unroll
    for (int it = 0; it < 4; it++) {
        int idx = it * 256 + tid;       // 0..1023
        int r = idx >> 4;               // 0..63
        int c4 = (idx & 15) * 4;        // 0,4,...,60
        float4 v = *(const float4*)(s + (size_t)r * C + c4);
        tl[c4 + 0][r] = v.x;
        tl[c4 + 1][r] = v.y;
        tl[c4 + 2][r] = v.z;
        tl[c4 + 3][r] = v.w;
    }
    __syncthreads();
    u16* d = dst + (size_t)e * C * R + (size_t)c0 * R + r0;
#pragma unroll
    for (int it = 0; it < 2; it++) {
        int idx = it * 256 + tid;       // 0..511
        int c = idx >> 3;               // 0..63
        int rg = (idx & 7) * 8;         // 0,8,...,56
        u32 o[4];
#pragma unroll
        for (int p = 0; p < 4; p++)
            o[p] = (u32)f2bf(tl[c][rg + 2 * p]) | ((u32)f2bf(tl[c][rg + 2 * p + 1]) << 16);
        *(uint4*)(d + (size_t)c * R + rg) = *(uint4*)o;
    }
}

// ===================== flatmm grouped GEMMs (no LDS operand staging) =====================
// 128x128 block tile, 4 waves (each 64x64, acc 4x4 of 16x16x32 MFMA).
// Operand fragments load DIRECTLY global->VGPR (16-lane x 64B segments, K-contiguous),
// register double-buffered (slice t+1 loads in flight during slice t MFMAs).
// No barriers in the K-loop; LDS holds only the 128-entry token list (+weights).

// ---------------- GEMM1: h1 = gelu(x_gathered @ w1) ----------------
// grid: x=mt(16) fastest (concurrent blocks share the B panel), y=nt(32), z=e(8)
__global__ __launch_bounds__(256) void gemm1_kernel(
    const u16* __restrict__ xb, const u16* __restrict__ w1t,
    const int* __restrict__ counts, const int* __restrict__ offs,
    const int* __restrict__ tlist, u16* __restrict__ h1b)
{
    const int mt = blockIdx.x, nt = blockIdx.y, e = blockIdx.z;
    const int cnt = counts[e];
    if (mt * 128 >= cnt) return;

    __shared__ int toks[128];
    const int tid = threadIdx.x, lane = tid & 63, wv = tid >> 6;
    if (tid < 128) toks[tid] = tlist[e * T_TOK + min(mt * 128 + tid, cnt - 1)];
    __syncthreads();

    const int wm = wv & 1, wn = wv >> 1;
    const int kq = (lane >> 4) * 8;       // k-subchunk within a 32-k slice (u16 units)

    u32 aoff[4], boff[4];
#pragma unroll
    for (int i = 0; i < 4; i++) {
        int m = wm * 64 + i * 16 + (lane & 15);
        aoff[i] = (u32)toks[m] * HID + kq;
    }
#pragma unroll
    for (int j = 0; j < 4; j++) {
        int n = nt * 128 + wn * 64 + j * 16 + (lane & 15);
        boff[j] = ((u32)e * INTER + (u32)n) * HID + kq;
    }

    f32x4 acc[4][4] = {};
    bf16x8 a0[4], b0[4], a1[4], b1[4];

#pragma unroll
    for (int i = 0; i < 4; i++) a0[i] = *(const bf16x8*)(xb + aoff[i]);
#pragma unroll
    for (int j = 0; j < 4; j++) b0[j] = *(const bf16x8*)(w1t + boff[j]);

    const int NT = HID / 32;   // 32 slices, even
#pragma unroll 1
    for (int t = 0; t < NT; t += 2) {
        // prefetch slice t+1 while computing slice t
#pragma unroll
        for (int i = 0; i < 4; i++) a1[i] = *(const bf16x8*)(xb + aoff[i] + (t + 1) * 32);
#pragma unroll
        for (int j = 0; j < 4; j++) b1[j] = *(const bf16x8*)(w1t + boff[j] + (t + 1) * 32);
#pragma unroll
        for (int i = 0; i < 4; i++)
#pragma unroll
            for (int j = 0; j < 4; j++)
                acc[i][j] = __builtin_amdgcn_mfma_f32_16x16x32_bf16(
                    a0[i], b0[j], acc[i][j], 0, 0, 0);
        if (t + 2 < NT) {
#pragma unroll
            for (int i = 0; i < 4; i++) a0[i] = *(const bf16x8*)(xb + aoff[i] + (t + 2) * 32);
#pragma unroll
            for (int j = 0; j < 4; j++) b0[j] = *(const bf16x8*)(w1t + boff[j] + (t + 2) * 32);
        }
#pragma unroll
        for (int i = 0; i < 4; i++)
#pragma unroll
            for (int j = 0; j < 4; j++)
                acc[i][j] = __builtin_amdgcn_mfma_f32_16x16x32_bf16(
                    a1[i], b1[j], acc[i][j], 0, 0, 0);
    }

    const int pb = offs[e] + mt * 128;
    const int rem = cnt - mt * 128;
    const bool full = (rem >= 128);
#pragma unroll
    for (int i = 0; i < 4; i++) {
        const int mb = wm * 64 + i * 16 + ((lane >> 4) << 2);
#pragma unroll
        for (int j = 0; j < 4; j++) {
            const int n = nt * 128 + wn * 64 + j * 16 + (lane & 15);
#pragma unroll
            for (int r = 0; r < 4; r++) {
                const int m = mb + r;
                if (full || m < rem)
                    h1b[(size_t)(pb + m) * INTER + n] = f2bf(fast_gelu(acc[i][j][r]));
            }
        }
    }
}

// -------- GEMM2: out += weight * (h1 @ w2), split-K=2, atomics -----
// grid: x=mt(16), y = nt(8) | ks<<3 (16), z=e(8)
__global__ __launch_bounds__(256) void gemm2_kernel(
    const u16* __restrict__ h1b, const u16* __restrict__ w2t,
    const int* __restrict__ counts, const int* __restrict__ offs,
    const int* __restrict__ tlist, const float* __restrict__ wlist,
    float* __restrict__ out)
{
    const int mt = blockIdx.x;
    const int nt = blockIdx.y & 7, ks = blockIdx.y >> 3;
    const int e = blockIdx.z;
    const int cnt = counts[e];
    if (mt * 128 >= cnt) return;

    __shared__ int toks[128];
    __shared__ float wgt[128];
    const int tid = threadIdx.x, lane = tid & 63, wv = tid >> 6;
    if (tid < 128) {
        int gi = e * T_TOK + min(mt * 128 + tid, cnt - 1);
        toks[tid] = tlist[gi];
        wgt[tid]  = wlist[gi];
    }
    __syncthreads();

    const int wm = wv & 1, wn = wv >> 1;
    const int kq = (lane >> 4) * 8;
    const u32 kbase = (u32)ks * (INTER / 2);
    const int prow = offs[e];

    u32 aoff[4], boff[4];
#pragma unroll
    for (int i = 0; i < 4; i++) {
        int m = wm * 64 + i * 16 + (lane & 15);
        int row = prow + min(mt * 128 + m, cnt - 1);
        aoff[i] = (u32)row * INTER + kbase + kq;
    }
#pragma unroll
    for (int j = 0; j < 4; j++) {
        int n = nt * 128 + wn * 64 + j * 16 + (lane & 15);
        boff[j] = ((u32)e * HID + (u32)n) * INTER + kbase + kq;
    }

    f32x4 acc[4][4] = {};
    bf16x8 a0[4], b0[4], a1[4], b1[4];

#pragma unroll
    for (int i = 0; i < 4; i++) a0[i] = *(const bf16x8*)(h1b + aoff[i]);
#pragma unroll
    for (int j = 0; j < 4; j++) b0[j] = *(const bf16x8*)(w2t + boff[j]);

    const int NT = (INTER / 2) / 32;   // 64 slices, even
#pragma unroll 1
    for (int t = 0; t < NT; t += 2) {
#pragma unroll
        for (int i = 0; i < 4; i++) a1[i] = *(const bf16x8*)(h1b + aoff[i] + (t + 1) * 32);
#pragma unroll
        for (int j = 0; j < 4; j++) b1[j] = *(const bf16x8*)(w2t + boff[j] + (t + 1) * 32);
#pragma unroll
        for (int i = 0; i < 4; i++)
#pragma unroll
            for (int j = 0; j < 4; j++)
                acc[i][j] = __builtin_amdgcn_mfma_f32_16x16x32_bf16(
                    a0[i], b0[j], acc[i][j], 0, 0, 0);
        if (t + 2 < NT) {
#pragma unroll
            for (int i = 0; i < 4; i++) a0[i] = *(const bf16x8*)(h1b + aoff[i] + (t + 2) * 32);
#pragma unroll
            for (int j = 0; j < 4; j++) b0[j] = *(const bf16x8*)(w2t + boff[j] + (t + 2) * 32);
        }
#pragma unroll
        for (int i = 0; i < 4; i++)
#pragma unroll
            for (int j = 0; j < 4; j++)
                acc[i][j] = __builtin_amdgcn_mfma_f32_16x16x32_bf16(
                    a1[i], b1[j], acc[i][j], 0, 0, 0);
    }

    const int rem = cnt - mt * 128;
    const bool full = (rem >= 128);
#pragma unroll
    for (int i = 0; i < 4; i++) {
        const int mb = wm * 64 + i * 16 + ((lane >> 4) << 2);
#pragma unroll
        for (int j = 0; j < 4; j++) {
            const int n = nt * 128 + wn * 64 + j * 16 + (lane & 15);
#pragma unroll
            for (int r = 0; r < 4; r++) {
                const int m = mb + r;
                if (full || m < rem)
                    atomicAdd(&out[(size_t)toks[m] * HID + n], acc[i][j][r] * wgt[m]);
            }
        }
    }
}

extern "C" void kernel_launch(void* const* d_in, const int* in_sizes, int n_in,
                              void* d_out, int out_size, void* d_ws, size_t ws_size,
                              hipStream_t stream)
{
    const float* x  = (const float*)d_in[0];   // [4,1024,1024]
    const float* gw = (const float*)d_in[1];   // [1024,8]
    const float* w1 = (const float*)d_in[2];   // [8,1024,4096]
    const float* w2 = (const float*)d_in[3];   // [8,4096,1024]
    float* out    = (float*)d_out;             // 4194304 out + 32768 logits
    float* logits = out + 4194304;

    char* ws = (char*)d_ws;
    int*   counts = (int*)ws;
    int*   offs   = (int*)(ws + 256);
    int*   tlist  = (int*)(ws + 1024);
    float* wlist  = (float*)(ws + 132096);
    u16*   xb     = (u16*)(ws + 263168);
    u16*   w1t    = (u16*)(ws + 8651776);
    u16*   w2t    = (u16*)(ws + 75760640);
    u16*   h1b    = (u16*)(ws + 142869504);

    if (ws_size < WS_NEEDED) return;

    hipMemsetAsync(out, 0, 4194304 * sizeof(float), stream);
    hipMemsetAsync(counts, 0, 256, stream);

    router_kernel<<<1024, 256, 0, stream>>>(x, gw, logits, counts, tlist, wlist);
    scan_kernel<<<1, 64, 0, stream>>>(counts, offs);
    convert_x_kernel<<<2048, 256, 0, stream>>>(x, xb);
    // w1 [E][H=1024][I=4096] -> w1t [E][I][H]
    transpose_convert_kernel<<<dim3(64, 16, 8), 256, 0, stream>>>(w1, w1t, HID, INTER);
    // w2 [E][I=4096][H=1024] -> w2t [E][H][I]
    transpose_convert_kernel<<<dim3(16, 64, 8), 256, 0, stream>>>(w2, w2t, INTER, HID);

    // gemm1: x=mt(16) fastest, y=nt(32), z=e(8)
    gemm1_kernel<<<dim3(16, 32, 8), 256, 0, stream>>>(xb, w1t, counts, offs, tlist, h1b);
    // gemm2: x=mt(16), y=nt(8)|ks<<3 (16), z=e(8)
    gemm2_kernel<<<dim3(16, 16, 8), 256, 0, stream>>>(h1b, w2t, counts, offs, tlist, wlist, out);
}

// Round 4
// 683.333 us; speedup vs baseline: 1.9918x; 1.9918x over previous
//
#include <hip/hip_runtime.h>
#include <hip/hip_bf16.h>
#include <math.h>

typedef unsigned short u16;
typedef unsigned int u32;
typedef __bf16 bf16x8 __attribute__((ext_vector_type(8)));
typedef float f32x4 __attribute__((ext_vector_type(4)));

#define T_TOK 4096
#define HID   1024
#define INTER 4096
#define NEXP  8

// ---------------- workspace layout (bytes) ----------------
// counts @ 0          (32 B used)
// tlist  @ 1024       (8*4096*4   = 131072) -> ends 132096
// sel    @ 132096     (4096*2*4   =  32768) -> ends 164864   [packed (e | p<<3) per token-slot]
// xb     @ 263168     (4096*1024*2 = 8.4MB)
// w1t    @ 8651776    (67.1MB)  -- ALIASED by y (2*8192*1024 f32 = 67.1MB) after gemm1
// w2t    @ 75760640   (67.1MB)
// h1b    @ 142869504  (67.1MB)  -> ends 209978368
#define WS_NEEDED 209978368ull

__device__ __forceinline__ u16 f2bf(float f) {
    u32 u = __builtin_bit_cast(u32, f);
    u += 0x7FFFu + ((u >> 16) & 1u);   // round-to-nearest-even
    return (u16)(u >> 16);
}

__device__ __forceinline__ void gl2lds16(const void* g, void* l) {
    __builtin_amdgcn_global_load_lds(
        (const __attribute__((address_space(1))) u32*)g,
        (__attribute__((address_space(3))) u32*)l, 16, 0, 0);
}

// fast exact-enough gelu: tanh approximation, stable rational form.
__device__ __forceinline__ float fast_gelu(float v) {
    float u2 = v * (-1.5957691216f - 0.0713548163f * v * v);  // -2u
    return v / (1.0f + __expf(u2));
}

// ---------- router: fp32 logits + top-2 lists + fused x->bf16 convert ----------
__global__ __launch_bounds__(256) void router_kernel(
    const float* __restrict__ x, const float* __restrict__ gw,
    float* __restrict__ logits, int* __restrict__ counts,
    int* __restrict__ tlist, u32* __restrict__ sel, u16* __restrict__ xb)
{
    const int lane = threadIdx.x & 63, wv = threadIdx.x >> 6;
    const int t = blockIdx.x * 4 + wv;
    const float* xr = x + (size_t)t * HID;
    u16* xw = xb + (size_t)t * HID;
    float a[8] = {0.f,0.f,0.f,0.f,0.f,0.f,0.f,0.f};
    for (int h = lane; h < HID; h += 64) {
        float xv = xr[h];
        xw[h] = f2bf(xv);                       // fused bf16 convert
        const float4* g4 = (const float4*)(gw + h * 8);
        float4 g0 = g4[0], g1 = g4[1];
        a[0] += xv * g0.x; a[1] += xv * g0.y; a[2] += xv * g0.z; a[3] += xv * g0.w;
        a[4] += xv * g1.x; a[5] += xv * g1.y; a[6] += xv * g1.z; a[7] += xv * g1.w;
    }
#pragma unroll
    for (int e = 0; e < 8; e++) {
        float v = a[e];
        for (int o = 32; o > 0; o >>= 1) v += __shfl_down(v, o, 64);
        a[e] = v;
    }
    if (lane == 0) {
#pragma unroll
        for (int e = 0; e < 8; e++) logits[(size_t)t * 8 + e] = a[e];
        int e1 = 0; float b1 = a[0];
        for (int e = 1; e < 8; e++) if (a[e] > b1) { b1 = a[e]; e1 = e; }
        int e2 = -1; float b2 = -1e30f;
        for (int e = 0; e < 8; e++) if (e != e1 && a[e] > b2) { b2 = a[e]; e2 = e; }
        int p = atomicAdd(&counts[e1], 1);
        tlist[e1 * T_TOK + p] = t;
        sel[2 * t + 0] = (u32)e1 | ((u32)p << 3);
        p = atomicAdd(&counts[e2], 1);
        tlist[e2 * T_TOK + p] = t;
        sel[2 * t + 1] = (u32)e2 | ((u32)p << 3);
    }
}

// ------- transpose + convert: src[E][R][C] f32 -> dst[E][C][R] bf16 -------
__global__ __launch_bounds__(256) void transpose_convert_kernel(
    const float* __restrict__ src, u16* __restrict__ dst, int R, int C)
{
    __shared__ float tl[64][65];   // [c][r], +1 pad
    const int e = blockIdx.z;
    const int c0 = blockIdx.x * 64, r0 = blockIdx.y * 64;
    const float* s = src + (size_t)e * R * C + (size_t)r0 * C + c0;
    const int tid = threadIdx.x;
#pragma unroll
    for (int it = 0; it < 4; it++) {
        int idx = it * 256 + tid;       // 0..1023
        int r = idx >> 4;               // 0..63
        int c4 = (idx & 15) * 4;        // 0,4,...,60
        float4 v = *(const float4*)(s + (size_t)r * C + c4);
        tl[c4 + 0][r] = v.x;
        tl[c4 + 1][r] = v.y;
        tl[c4 + 2][r] = v.z;
        tl[c4 + 3][r] = v.w;
    }
    __syncthreads();
    u16* d = dst + (size_t)e * C * R + (size_t)c0 * R + r0;
#pragma unroll
    for (int it = 0; it < 2; it++) {
        int idx = it * 256 + tid;       // 0..511
        int c = idx >> 3;               // 0..63
        int rg = (idx & 7) * 8;         // 0,8,...,56
        u32 o[4];
#pragma unroll
        for (int p = 0; p < 4; p++)
            o[p] = (u32)f2bf(tl[c][rg + 2 * p]) | ((u32)f2bf(tl[c][rg + 2 * p + 1]) << 16);
        *(uint4*)(d + (size_t)c * R + rg) = *(uint4*)o;
    }
}

// ---------------- GEMM1: h1 = gelu(x_gathered @ w1), bf16 MFMA ----------------
// (round-0 proven structure: 128x128 tile, 4 waves, 2 barriers/K-step, 4 blocks/CU)
__global__ __launch_bounds__(256, 1) void gemm1_kernel(
    const u16* __restrict__ xb, const u16* __restrict__ w1t,
    const int* __restrict__ counts, const int* __restrict__ tlist,
    u16* __restrict__ h1b)
{
    const int e = blockIdx.z, mt = blockIdx.y, nt = blockIdx.x;
    const int cnt = counts[e];
    if (mt * 128 >= cnt) return;
    __shared__ __align__(16) u16 As[8192];   // [m 0..127][k-chunk swizzled]
    __shared__ __align__(16) u16 Bs[8192];   // [n 0..127][k-chunk swizzled]
    __shared__ int toks[128];
    const int tid = threadIdx.x, lane = tid & 63, wv = tid >> 6;
    if (tid < 128) toks[tid] = tlist[e * T_TOK + min(mt * 128 + tid, cnt - 1)];
    __syncthreads();

    f32x4 acc[4][4] = {};
    const int wm = wv & 1, wn = wv >> 1;
    const int sj = tid >> 3, sp = tid & 7;

    size_t abase[4], bbase[4];
    const u16* w1base = w1t + ((size_t)e * INTER + (size_t)nt * 128) * HID;
#pragma unroll
    for (int j = 0; j < 4; j++) {
        int m = j * 32 + sj;
        abase[j] = (size_t)toks[m] * HID + ((sp - m) & 7) * 8;
        bbase[j] = (size_t)m * HID + ((sp - m) & 7) * 8;
    }

    for (int h0 = 0; h0 < HID; h0 += 64) {
#pragma unroll
        for (int j = 0; j < 4; j++)
            gl2lds16(xb + abase[j] + h0, &As[j * 2048 + wv * 512]);
#pragma unroll
        for (int j = 0; j < 4; j++)
            gl2lds16(w1base + bbase[j] + h0, &Bs[j * 2048 + wv * 512]);
        __syncthreads();
#pragma unroll
        for (int kk = 0; kk < 2; kk++) {
            bf16x8 a[4], b[4];
            const int jjb = kk * 4 + (lane >> 4);
#pragma unroll
            for (int i = 0; i < 4; i++) {
                int m = wm * 64 + i * 16 + (lane & 15);
                a[i] = *(const bf16x8*)&As[m * 64 + ((jjb + m) & 7) * 8];
            }
#pragma unroll
            for (int i = 0; i < 4; i++) {
                int n = wn * 64 + i * 16 + (lane & 15);
                b[i] = *(const bf16x8*)&Bs[n * 64 + ((jjb + n) & 7) * 8];
            }
#pragma unroll
            for (int i = 0; i < 4; i++)
#pragma unroll
                for (int j = 0; j < 4; j++)
                    acc[i][j] = __builtin_amdgcn_mfma_f32_16x16x32_bf16(
                        a[i], b[j], acc[i][j], 0, 0, 0);
        }
        __syncthreads();
    }

    int prow = 0;
#pragma unroll
    for (int i = 0; i < 8; i++) prow += (i < e) ? counts[i] : 0;
    const int pb = prow + mt * 128;
    const bool full = (mt * 128 + 128 <= cnt);
#pragma unroll
    for (int i = 0; i < 4; i++) {
        const int mb = wm * 64 + i * 16 + ((lane >> 4) << 2);
#pragma unroll
        for (int j = 0; j < 4; j++) {
            const int n = nt * 128 + wn * 64 + j * 16 + (lane & 15);
#pragma unroll
            for (int r = 0; r < 4; r++) {
                const int m = mb + r;
                if (full || mt * 128 + m < cnt) {
                    h1b[(size_t)(pb + m) * INTER + n] = f2bf(fast_gelu(acc[i][j][r]));
                }
            }
        }
    }
}

// -------- GEMM2: y_ks[row] = h1 @ w2 (per k-split), plain f32 stores, no atomics -----
__global__ __launch_bounds__(256, 1) void gemm2_kernel(
    const u16* __restrict__ h1b, const u16* __restrict__ w2t,
    const int* __restrict__ counts, const int* __restrict__ tlist,
    float* __restrict__ y)
{
    const int e = blockIdx.z, mt = blockIdx.y;
    const int nt = blockIdx.x & 7, ks = blockIdx.x >> 3;
    const int cnt = counts[e];
    if (mt * 128 >= cnt) return;
    __shared__ __align__(16) u16 As[8192];
    __shared__ __align__(16) u16 Bs[8192];
    const int tid = threadIdx.x, lane = tid & 63, wv = tid >> 6;

    int prow = 0;
#pragma unroll
    for (int i = 0; i < 8; i++) prow += (i < e) ? counts[i] : 0;

    f32x4 acc[4][4] = {};
    const int wm = wv & 1, wn = wv >> 1;
    const int sj = tid >> 3, sp = tid & 7;

    size_t abase[4], bbase[4];
    const u16* w2base = w2t + ((size_t)e * HID + (size_t)nt * 128) * INTER;
#pragma unroll
    for (int j = 0; j < 4; j++) {
        int m = j * 32 + sj;
        int row = prow + min(mt * 128 + m, cnt - 1);
        abase[j] = (size_t)row * INTER + ((sp - m) & 7) * 8;
        bbase[j] = (size_t)m * INTER + ((sp - m) & 7) * 8;
    }

    const int i_lo = ks * (INTER / 2), i_hi = i_lo + (INTER / 2);
    for (int i0 = i_lo; i0 < i_hi; i0 += 64) {
#pragma unroll
        for (int j = 0; j < 4; j++)
            gl2lds16(h1b + abase[j] + i0, &As[j * 2048 + wv * 512]);
#pragma unroll
        for (int j = 0; j < 4; j++)
            gl2lds16(w2base + bbase[j] + i0, &Bs[j * 2048 + wv * 512]);
        __syncthreads();
#pragma unroll
        for (int kk = 0; kk < 2; kk++) {
            bf16x8 a[4], b[4];
            const int jjb = kk * 4 + (lane >> 4);
#pragma unroll
            for (int i = 0; i < 4; i++) {
                int m = wm * 64 + i * 16 + (lane & 15);
                a[i] = *(const bf16x8*)&As[m * 64 + ((jjb + m) & 7) * 8];
            }
#pragma unroll
            for (int i = 0; i < 4; i++) {
                int n = wn * 64 + i * 16 + (lane & 15);
                b[i] = *(const bf16x8*)&Bs[n * 64 + ((jjb + n) & 7) * 8];
            }
#pragma unroll
            for (int i = 0; i < 4; i++)
#pragma unroll
                for (int j = 0; j < 4; j++)
                    acc[i][j] = __builtin_amdgcn_mfma_f32_16x16x32_bf16(
                        a[i], b[j], acc[i][j], 0, 0, 0);
        }
        __syncthreads();
    }

    float* yk = y + (size_t)ks * (8192ull * HID);
    const bool full = (mt * 128 + 128 <= cnt);
#pragma unroll
    for (int i = 0; i < 4; i++) {
        const int mb = wm * 64 + i * 16 + ((lane >> 4) << 2);
#pragma unroll
        for (int j = 0; j < 4; j++) {
            const int n = nt * 128 + wn * 64 + j * 16 + (lane & 15);
#pragma unroll
            for (int r = 0; r < 4; r++) {
                const int m = mb + r;
                if (full || mt * 128 + m < cnt) {
                    yk[(size_t)(prow + mt * 128 + m) * HID + n] = acc[i][j][r];
                }
            }
        }
    }
}

// -------- combine: out[t] = w0*(y0[g0]+y1[g0]) + w1*(y0[g1]+y1[g1]) --------
// one block per token; weights recomputed from logits (bit-identical to router math)
__global__ __launch_bounds__(256) void combine_kernel(
    const float* __restrict__ y, const u32* __restrict__ sel,
    const int* __restrict__ counts, const float* __restrict__ logits,
    float* __restrict__ out)
{
    const int t = blockIdx.x;
    const u32 s0 = sel[2 * t + 0], s1 = sel[2 * t + 1];
    const int e0 = s0 & 7, p0 = s0 >> 3;
    const int e1 = s1 & 7, p1 = s1 >> 3;
    int off0 = 0, off1 = 0;
#pragma unroll
    for (int i = 0; i < 8; i++) {
        int c = counts[i];
        off0 += (i < e0) ? c : 0;
        off1 += (i < e1) ? c : 0;
    }
    const size_t g0 = (size_t)(off0 + p0) * HID;
    const size_t g1 = (size_t)(off1 + p1) * HID;
    const float la = logits[(size_t)t * 8 + e0];   // primary (slot 0) logit
    const float lb = logits[(size_t)t * 8 + e1];
    const float w0 = 1.0f / (1.0f + expf(lb - la));
    const float w1 = 1.0f - w0;

    const int c = threadIdx.x * 4;
    const float* y1p = y + 8192ull * HID;
    f32x4 a0 = *(const f32x4*)(y + g0 + c);
    f32x4 a1 = *(const f32x4*)(y1p + g0 + c);
    f32x4 b0 = *(const f32x4*)(y + g1 + c);
    f32x4 b1 = *(const f32x4*)(y1p + g1 + c);
    f32x4 o = w0 * (a0 + a1) + w1 * (b0 + b1);
    *(f32x4*)(out + (size_t)t * HID + c) = o;
}

extern "C" void kernel_launch(void* const* d_in, const int* in_sizes, int n_in,
                              void* d_out, int out_size, void* d_ws, size_t ws_size,
                              hipStream_t stream)
{
    const float* x  = (const float*)d_in[0];   // [4,1024,1024]
    const float* gw = (const float*)d_in[1];   // [1024,8]
    const float* w1 = (const float*)d_in[2];   // [8,1024,4096]
    const float* w2 = (const float*)d_in[3];   // [8,4096,1024]
    float* out    = (float*)d_out;             // 4194304 out + 32768 logits
    float* logits = out + 4194304;

    char* ws = (char*)d_ws;
    int*   counts = (int*)ws;
    int*   tlist  = (int*)(ws + 1024);
    u32*   sel    = (u32*)(ws + 132096);
    u16*   xb     = (u16*)(ws + 263168);
    u16*   w1t    = (u16*)(ws + 8651776);
    float* y      = (float*)(ws + 8651776);     // aliases w1t (dead after gemm1)
    u16*   w2t    = (u16*)(ws + 75760640);
    u16*   h1b    = (u16*)(ws + 142869504);

    if (ws_size < WS_NEEDED) return;

    hipMemsetAsync(counts, 0, 256, stream);

    // router + fused x->bf16 convert
    router_kernel<<<1024, 256, 0, stream>>>(x, gw, logits, counts, tlist, sel, xb);
    // w1 [E][H=1024][I=4096] -> w1t [E][I][H]
    transpose_convert_kernel<<<dim3(64, 16, 8), 256, 0, stream>>>(w1, w1t, HID, INTER);
    // w2 [E][I=4096][H=1024] -> w2t [E][H][I]
    transpose_convert_kernel<<<dim3(16, 64, 8), 256, 0, stream>>>(w2, w2t, INTER, HID);

    // gemm1: grid x=nt(32), y=mt(16), z=e(8)
    gemm1_kernel<<<dim3(32, 16, 8), 256, 0, stream>>>(xb, w1t, counts, tlist, h1b);
    // gemm2: grid x = nt(8) + 8*ks(2), y=mt(16), z=e(8); writes y (w1t region now dead)
    gemm2_kernel<<<dim3(16, 16, 8), 256, 0, stream>>>(h1b, w2t, counts, tlist, y);
    // combine: one block per token
    combine_kernel<<<T_TOK, 256, 0, stream>>>(y, sel, counts, logits, out);
}

// Round 5
// 664.825 us; speedup vs baseline: 2.0473x; 1.0278x over previous
//
#include <hip/hip_runtime.h>
#include <hip/hip_bf16.h>
#include <math.h>

typedef unsigned short u16;
typedef unsigned int u32;
typedef __bf16 bf16x8 __attribute__((ext_vector_type(8)));
typedef float f32x4 __attribute__((ext_vector_type(4)));

#define T_TOK 4096
#define HID   1024
#define INTER 4096
#define NEXP  8

// ---------------- workspace layout (bytes) ----------------
// counts @ 0          (32 B used)
// tlist  @ 1024       (8*4096*4   = 131072) -> ends 132096
// sel    @ 132096     (4096*2*4   =  32768) -> ends 164864   [packed (e | p<<3) per token-slot]
// xb     @ 263168     (4096*1024*2 = 8.4MB)
// w1t    @ 8651776    (67.1MB)  -- ALIASED by y (2*8192*1024 f32 = 67.1MB) after gemm1
// w2t    @ 75760640   (67.1MB)
// h1b    @ 142869504  (67.1MB)  -> ends 209978368
#define WS_NEEDED 209978368ull

// native bf16 cast (RTNE) -> compiler emits v_cvt_pk_bf16_f32 for pairs
__device__ __forceinline__ u16 bfc(float f) {
    return __builtin_bit_cast(u16, (__bf16)f);
}
__device__ __forceinline__ u32 pk2bf(float a, float b) {
    return (u32)__builtin_bit_cast(u16, (__bf16)a)
         | ((u32)__builtin_bit_cast(u16, (__bf16)b) << 16);
}

__device__ __forceinline__ void gl2lds16(const void* g, void* l) {
    __builtin_amdgcn_global_load_lds(
        (const __attribute__((address_space(1))) u32*)g,
        (__attribute__((address_space(3))) u32*)l, 16, 0, 0);
}

// fast exact-enough gelu: tanh approximation, stable rational form.
__device__ __forceinline__ float fast_gelu(float v) {
    float u2 = v * (-1.5957691216f - 0.0713548163f * v * v);  // -2u
    return v / (1.0f + __expf(u2));
}

// ========== fused preprocessing: router + x->bf16 + both weight transposes ==========
// blocks [0,1024):           router, 4 tokens/block (one wave each), fused x->xb convert
// blocks [1024,1024+8192):   w1 [E][H][I] f32 -> w1t [E][I][H] bf16   (R=HID,  C=INTER)
// blocks [9216,9216+8192):   w2 [E][I][H] f32 -> w2t [E][H][I] bf16   (R=INTER,C=HID)
#define RTR_BLK 1024
#define TW_BLK  8192

__global__ __launch_bounds__(256) void preproc_kernel(
    const float* __restrict__ x, const float* __restrict__ gw,
    const float* __restrict__ w1, const float* __restrict__ w2,
    float* __restrict__ logits, int* __restrict__ counts,
    int* __restrict__ tlist, u32* __restrict__ sel, u16* __restrict__ xb,
    u16* __restrict__ w1t, u16* __restrict__ w2t)
{
    __shared__ float tl[64][65];   // transpose tile [c][r], +1 pad (router blocks unused)
    const int bid = blockIdx.x;
    const int tid = threadIdx.x;

    if (bid < RTR_BLK) {
        // ---------------- router ----------------
        const int lane = tid & 63, wv = tid >> 6;
        const int t = bid * 4 + wv;
        const float* xr = x + (size_t)t * HID;
        u16* xw = xb + (size_t)t * HID;
        float a[8] = {0.f,0.f,0.f,0.f,0.f,0.f,0.f,0.f};
        for (int h = lane; h < HID; h += 64) {
            float xv = xr[h];
            xw[h] = bfc(xv);                       // fused bf16 convert
            const float4* g4 = (const float4*)(gw + h * 8);
            float4 g0 = g4[0], g1 = g4[1];
            a[0] += xv * g0.x; a[1] += xv * g0.y; a[2] += xv * g0.z; a[3] += xv * g0.w;
            a[4] += xv * g1.x; a[5] += xv * g1.y; a[6] += xv * g1.z; a[7] += xv * g1.w;
        }
#pragma unroll
        for (int e = 0; e < 8; e++) {
            float v = a[e];
            for (int o = 32; o > 0; o >>= 1) v += __shfl_down(v, o, 64);
            a[e] = v;
        }
        if (lane == 0) {
#pragma unroll
            for (int e = 0; e < 8; e++) logits[(size_t)t * 8 + e] = a[e];
            int e1 = 0; float b1 = a[0];
            for (int e = 1; e < 8; e++) if (a[e] > b1) { b1 = a[e]; e1 = e; }
            int e2 = -1; float b2 = -1e30f;
            for (int e = 0; e < 8; e++) if (e != e1 && a[e] > b2) { b2 = a[e]; e2 = e; }
            int p = atomicAdd(&counts[e1], 1);
            tlist[e1 * T_TOK + p] = t;
            sel[2 * t + 0] = (u32)e1 | ((u32)p << 3);
            p = atomicAdd(&counts[e2], 1);
            tlist[e2 * T_TOK + p] = t;
            sel[2 * t + 1] = (u32)e2 | ((u32)p << 3);
        }
        return;
    }

    // ---------------- weight transpose+convert ----------------
    const float* src; u16* dst; int R, C, id;
    if (bid < RTR_BLK + TW_BLK) { id = bid - RTR_BLK;          src = w1; dst = w1t; R = HID;   C = INTER; }
    else                        { id = bid - RTR_BLK - TW_BLK; src = w2; dst = w2t; R = INTER; C = HID;   }
    const int cpb = C >> 6, rpb = R >> 6;
    const int bx = id % cpb;
    const int tmp = id / cpb;
    const int by = tmp % rpb;
    const int e  = tmp / rpb;
    const int c0 = bx * 64, r0 = by * 64;
    const float* s = src + (size_t)e * R * C + (size_t)r0 * C + c0;
#pragma unroll
    for (int it = 0; it < 4; it++) {
        int idx = it * 256 + tid;       // 0..1023
        int r = idx >> 4;               // 0..63
        int c4 = (idx & 15) * 4;        // 0,4,...,60
        float4 v = *(const float4*)(s + (size_t)r * C + c4);
        tl[c4 + 0][r] = v.x;
        tl[c4 + 1][r] = v.y;
        tl[c4 + 2][r] = v.z;
        tl[c4 + 3][r] = v.w;
    }
    __syncthreads();
    u16* d = dst + (size_t)e * C * R + (size_t)c0 * R + r0;
#pragma unroll
    for (int it = 0; it < 2; it++) {
        int idx = it * 256 + tid;       // 0..511
        int c = idx >> 3;               // 0..63
        int rg = (idx & 7) * 8;         // 0,8,...,56
        u32 o[4];
#pragma unroll
        for (int p = 0; p < 4; p++)
            o[p] = pk2bf(tl[c][rg + 2 * p], tl[c][rg + 2 * p + 1]);
        *(uint4*)(d + (size_t)c * R + rg) = *(uint4*)o;
    }
}

// ---------------- GEMM1: h1 = gelu(x_gathered @ w1), bf16 MFMA ----------------
// (round-0 proven structure: 128x128 tile, 4 waves, 2 barriers/K-step, 4 blocks/CU)
__global__ __launch_bounds__(256, 1) void gemm1_kernel(
    const u16* __restrict__ xb, const u16* __restrict__ w1t,
    const int* __restrict__ counts, const int* __restrict__ tlist,
    u16* __restrict__ h1b)
{
    const int e = blockIdx.z, mt = blockIdx.y, nt = blockIdx.x;
    const int cnt = counts[e];
    if (mt * 128 >= cnt) return;
    __shared__ __align__(16) u16 As[8192];   // [m 0..127][k-chunk swizzled]
    __shared__ __align__(16) u16 Bs[8192];   // [n 0..127][k-chunk swizzled]
    __shared__ int toks[128];
    const int tid = threadIdx.x, lane = tid & 63, wv = tid >> 6;
    if (tid < 128) toks[tid] = tlist[e * T_TOK + min(mt * 128 + tid, cnt - 1)];
    __syncthreads();

    f32x4 acc[4][4] = {};
    const int wm = wv & 1, wn = wv >> 1;
    const int sj = tid >> 3, sp = tid & 7;

    size_t abase[4], bbase[4];
    const u16* w1base = w1t + ((size_t)e * INTER + (size_t)nt * 128) * HID;
#pragma unroll
    for (int j = 0; j < 4; j++) {
        int m = j * 32 + sj;
        abase[j] = (size_t)toks[m] * HID + ((sp - m) & 7) * 8;
        bbase[j] = (size_t)m * HID + ((sp - m) & 7) * 8;
    }

    for (int h0 = 0; h0 < HID; h0 += 64) {
#pragma unroll
        for (int j = 0; j < 4; j++)
            gl2lds16(xb + abase[j] + h0, &As[j * 2048 + wv * 512]);
#pragma unroll
        for (int j = 0; j < 4; j++)
            gl2lds16(w1base + bbase[j] + h0, &Bs[j * 2048 + wv * 512]);
        __syncthreads();
#pragma unroll
        for (int kk = 0; kk < 2; kk++) {
            bf16x8 a[4], b[4];
            const int jjb = kk * 4 + (lane >> 4);
#pragma unroll
            for (int i = 0; i < 4; i++) {
                int m = wm * 64 + i * 16 + (lane & 15);
                a[i] = *(const bf16x8*)&As[m * 64 + ((jjb + m) & 7) * 8];
            }
#pragma unroll
            for (int i = 0; i < 4; i++) {
                int n = wn * 64 + i * 16 + (lane & 15);
                b[i] = *(const bf16x8*)&Bs[n * 64 + ((jjb + n) & 7) * 8];
            }
#pragma unroll
            for (int i = 0; i < 4; i++)
#pragma unroll
                for (int j = 0; j < 4; j++)
                    acc[i][j] = __builtin_amdgcn_mfma_f32_16x16x32_bf16(
                        a[i], b[j], acc[i][j], 0, 0, 0);
        }
        __syncthreads();
    }

    int prow = 0;
#pragma unroll
    for (int i = 0; i < 8; i++) prow += (i < e) ? counts[i] : 0;
    const int pb = prow + mt * 128;
    const bool full = (mt * 128 + 128 <= cnt);
#pragma unroll
    for (int i = 0; i < 4; i++) {
        const int mb = wm * 64 + i * 16 + ((lane >> 4) << 2);
#pragma unroll
        for (int j = 0; j < 4; j++) {
            const int n = nt * 128 + wn * 64 + j * 16 + (lane & 15);
#pragma unroll
            for (int r = 0; r < 4; r++) {
                const int m = mb + r;
                if (full || mt * 128 + m < cnt) {
                    h1b[(size_t)(pb + m) * INTER + n] = bfc(fast_gelu(acc[i][j][r]));
                }
            }
        }
    }
}

// -------- GEMM2: y_ks[row] = h1 @ w2 (per k-split), plain f32 stores, no atomics -----
__global__ __launch_bounds__(256, 1) void gemm2_kernel(
    const u16* __restrict__ h1b, const u16* __restrict__ w2t,
    const int* __restrict__ counts, const int* __restrict__ tlist,
    float* __restrict__ y)
{
    const int e = blockIdx.z, mt = blockIdx.y;
    const int nt = blockIdx.x & 7, ks = blockIdx.x >> 3;
    const int cnt = counts[e];
    if (mt * 128 >= cnt) return;
    __shared__ __align__(16) u16 As[8192];
    __shared__ __align__(16) u16 Bs[8192];
    const int tid = threadIdx.x, lane = tid & 63, wv = tid >> 6;

    int prow = 0;
#pragma unroll
    for (int i = 0; i < 8; i++) prow += (i < e) ? counts[i] : 0;

    f32x4 acc[4][4] = {};
    const int wm = wv & 1, wn = wv >> 1;
    const int sj = tid >> 3, sp = tid & 7;

    size_t abase[4], bbase[4];
    const u16* w2base = w2t + ((size_t)e * HID + (size_t)nt * 128) * INTER;
#pragma unroll
    for (int j = 0; j < 4; j++) {
        int m = j * 32 + sj;
        int row = prow + min(mt * 128 + m, cnt - 1);
        abase[j] = (size_t)row * INTER + ((sp - m) & 7) * 8;
        bbase[j] = (size_t)m * INTER + ((sp - m) & 7) * 8;
    }

    const int i_lo = ks * (INTER / 2), i_hi = i_lo + (INTER / 2);
    for (int i0 = i_lo; i0 < i_hi; i0 += 64) {
#pragma unroll
        for (int j = 0; j < 4; j++)
            gl2lds16(h1b + abase[j] + i0, &As[j * 2048 + wv * 512]);
#pragma unroll
        for (int j = 0; j < 4; j++)
            gl2lds16(w2base + bbase[j] + i0, &Bs[j * 2048 + wv * 512]);
        __syncthreads();
#pragma unroll
        for (int kk = 0; kk < 2; kk++) {
            bf16x8 a[4], b[4];
            const int jjb = kk * 4 + (lane >> 4);
#pragma unroll
            for (int i = 0; i < 4; i++) {
                int m = wm * 64 + i * 16 + (lane & 15);
                a[i] = *(const bf16x8*)&As[m * 64 + ((jjb + m) & 7) * 8];
            }
#pragma unroll
            for (int i = 0; i < 4; i++) {
                int n = wn * 64 + i * 16 + (lane & 15);
                b[i] = *(const bf16x8*)&Bs[n * 64 + ((jjb + n) & 7) * 8];
            }
#pragma unroll
            for (int i = 0; i < 4; i++)
#pragma unroll
                for (int j = 0; j < 4; j++)
                    acc[i][j] = __builtin_amdgcn_mfma_f32_16x16x32_bf16(
                        a[i], b[j], acc[i][j], 0, 0, 0);
        }
        __syncthreads();
    }

    float* yk = y + (size_t)ks * (8192ull * HID);
    const bool full = (mt * 128 + 128 <= cnt);
#pragma unroll
    for (int i = 0; i < 4; i++) {
        const int mb = wm * 64 + i * 16 + ((lane >> 4) << 2);
#pragma unroll
        for (int j = 0; j < 4; j++) {
            const int n = nt * 128 + wn * 64 + j * 16 + (lane & 15);
#pragma unroll
            for (int r = 0; r < 4; r++) {
                const int m = mb + r;
                if (full || mt * 128 + m < cnt) {
                    yk[(size_t)(prow + mt * 128 + m) * HID + n] = acc[i][j][r];
                }
            }
        }
    }
}

// -------- combine: out[t] = w0*(y0[g0]+y1[g0]) + w1*(y0[g1]+y1[g1]) --------
// one block per token; weights recomputed from logits (bit-identical to router math)
__global__ __launch_bounds__(256) void combine_kernel(
    const float* __restrict__ y, const u32* __restrict__ sel,
    const int* __restrict__ counts, const float* __restrict__ logits,
    float* __restrict__ out)
{
    const int t = blockIdx.x;
    const u32 s0 = sel[2 * t + 0], s1 = sel[2 * t + 1];
    const int e0 = s0 & 7, p0 = s0 >> 3;
    const int e1 = s1 & 7, p1 = s1 >> 3;
    int off0 = 0, off1 = 0;
#pragma unroll
    for (int i = 0; i < 8; i++) {
        int c = counts[i];
        off0 += (i < e0) ? c : 0;
        off1 += (i < e1) ? c : 0;
    }
    const size_t g0 = (size_t)(off0 + p0) * HID;
    const size_t g1 = (size_t)(off1 + p1) * HID;
    const float la = logits[(size_t)t * 8 + e0];   // primary (slot 0) logit
    const float lb = logits[(size_t)t * 8 + e1];
    const float w0 = 1.0f / (1.0f + expf(lb - la));
    const float w1 = 1.0f - w0;

    const int c = threadIdx.x * 4;
    const float* y1p = y + 8192ull * HID;
    f32x4 a0 = *(const f32x4*)(y + g0 + c);
    f32x4 a1 = *(const f32x4*)(y1p + g0 + c);
    f32x4 b0 = *(const f32x4*)(y + g1 + c);
    f32x4 b1 = *(const f32x4*)(y1p + g1 + c);
    f32x4 o = w0 * (a0 + a1) + w1 * (b0 + b1);
    *(f32x4*)(out + (size_t)t * HID + c) = o;
}

extern "C" void kernel_launch(void* const* d_in, const int* in_sizes, int n_in,
                              void* d_out, int out_size, void* d_ws, size_t ws_size,
                              hipStream_t stream)
{
    const float* x  = (const float*)d_in[0];   // [4,1024,1024]
    const float* gw = (const float*)d_in[1];   // [1024,8]
    const float* w1 = (const float*)d_in[2];   // [8,1024,4096]
    const float* w2 = (const float*)d_in[3];   // [8,4096,1024]
    float* out    = (float*)d_out;             // 4194304 out + 32768 logits
    float* logits = out + 4194304;

    char* ws = (char*)d_ws;
    int*   counts = (int*)ws;
    int*   tlist  = (int*)(ws + 1024);
    u32*   sel    = (u32*)(ws + 132096);
    u16*   xb     = (u16*)(ws + 263168);
    u16*   w1t    = (u16*)(ws + 8651776);
    float* y      = (float*)(ws + 8651776);     // aliases w1t (dead after gemm1)
    u16*   w2t    = (u16*)(ws + 75760640);
    u16*   h1b    = (u16*)(ws + 142869504);

    if (ws_size < WS_NEEDED) return;

    hipMemsetAsync(counts, 0, 256, stream);

    // fused: router + x->bf16 + w1 transpose + w2 transpose
    preproc_kernel<<<RTR_BLK + 2 * TW_BLK, 256, 0, stream>>>(
        x, gw, w1, w2, logits, counts, tlist, sel, xb, w1t, w2t);

    // gemm1: grid x=nt(32), y=mt(16), z=e(8)
    gemm1_kernel<<<dim3(32, 16, 8), 256, 0, stream>>>(xb, w1t, counts, tlist, h1b);
    // gemm2: grid x = nt(8) + 8*ks(2), y=mt(16), z=e(8); writes y (w1t region now dead)
    gemm2_kernel<<<dim3(16, 16, 8), 256, 0, stream>>>(h1b, w2t, counts, tlist, y);
    // combine: one block per token
    combine_kernel<<<T_TOK, 256, 0, stream>>>(y, sel, counts, logits, out);
}

// Round 6
// 632.715 us; speedup vs baseline: 2.1512x; 1.0507x over previous
//
#include <hip/hip_runtime.h>
#include <hip/hip_bf16.h>
#include <math.h>

typedef unsigned short u16;
typedef unsigned int u32;
typedef __bf16 bf16x8 __attribute__((ext_vector_type(8)));
typedef float f32x4 __attribute__((ext_vector_type(4)));

#define T_TOK 4096
#define HID   1024
#define INTER 4096
#define NEXP  8

// ---------------- workspace layout (bytes) ----------------
// counts @ 0          (32 B used)
// tlist  @ 1024       (8*4096*4   = 131072) -> ends 132096
// sel    @ 132096     (4096*2*4   =  32768) -> ends 164864   [packed (e | p<<3) per token-slot]
// xb     @ 263168     (4096*1024*2 = 8.4MB)
// w1s    @ 8651776    (67.1MB, B-images for gemm1)  -- ALIASED by y (2*8192*1024 f32) after gemm1
// w2s    @ 75760640   (67.1MB, B-images for gemm2)
// h1b    @ 142869504  (67.1MB)  -> ends 209978368
#define WS_NEEDED 209978368ull

// native bf16 cast (RTNE) -> compiler emits v_cvt_pk_bf16_f32 for pairs
__device__ __forceinline__ u16 bfc(float f) {
    return __builtin_bit_cast(u16, (__bf16)f);
}
__device__ __forceinline__ u32 pk2bf(float a, float b) {
    return (u32)__builtin_bit_cast(u16, (__bf16)a)
         | ((u32)__builtin_bit_cast(u16, (__bf16)b) << 16);
}

__device__ __forceinline__ void gl2lds16(const void* g, void* l) {
    __builtin_amdgcn_global_load_lds(
        (const __attribute__((address_space(1))) u32*)g,
        (__attribute__((address_space(3))) u32*)l, 16, 0, 0);
}

// fast exact-enough gelu: tanh approximation, stable rational form.
__device__ __forceinline__ float fast_gelu(float v) {
    float u2 = v * (-1.5957691216f - 0.0713548163f * v * v);  // -2u
    return v / (1.0f + __expf(u2));
}

// ========== fused preprocessing: router + x->bf16 + weight->B-image builds ==========
// blocks [0,1024):           router, 4 tokens/block (one wave each), fused x->xb convert
// blocks [1024,1024+8192):   w1 [E][H][I] f32 -> w1s images (R=HID,  C=INTER)
// blocks [9216,9216+8192):   w2 [E][I][H] f32 -> w2s images (R=INTER,C=HID)
//
// B-image (16 KB) = the exact Bs-LDS byte content for one (e, nt, kstep):
//   img_u16[m*64 + sp*8 + i] = bf16( src[e][kstep*64 + ((sp-m)&7)*8 + i][nt*128 + m] )
// Each 64x64 transpose block emits one CONTIGUOUS 8 KB half-image (page-friendly),
// and GEMM B-staging becomes a purely sequential 16 KB stream per K-step.
#define RTR_BLK 1024
#define TW_BLK  8192

__global__ __launch_bounds__(256) void preproc_kernel(
    const float* __restrict__ x, const float* __restrict__ gw,
    const float* __restrict__ w1, const float* __restrict__ w2,
    float* __restrict__ logits, int* __restrict__ counts,
    int* __restrict__ tlist, u32* __restrict__ sel, u16* __restrict__ xb,
    u16* __restrict__ w1s, u16* __restrict__ w2s)
{
    __shared__ float tl[64][65];   // transpose tile [c][r], +1 pad (router blocks unused)
    const int bid = blockIdx.x;
    const int tid = threadIdx.x;

    if (bid < RTR_BLK) {
        // ---------------- router ----------------
        const int lane = tid & 63, wv = tid >> 6;
        const int t = bid * 4 + wv;
        const float* xr = x + (size_t)t * HID;
        u16* xw = xb + (size_t)t * HID;
        float a[8] = {0.f,0.f,0.f,0.f,0.f,0.f,0.f,0.f};
        for (int h = lane; h < HID; h += 64) {
            float xv = xr[h];
            xw[h] = bfc(xv);                       // fused bf16 convert
            const float4* g4 = (const float4*)(gw + h * 8);
            float4 g0 = g4[0], g1 = g4[1];
            a[0] += xv * g0.x; a[1] += xv * g0.y; a[2] += xv * g0.z; a[3] += xv * g0.w;
            a[4] += xv * g1.x; a[5] += xv * g1.y; a[6] += xv * g1.z; a[7] += xv * g1.w;
        }
#pragma unroll
        for (int e = 0; e < 8; e++) {
            float v = a[e];
            for (int o = 32; o > 0; o >>= 1) v += __shfl_down(v, o, 64);
            a[e] = v;
        }
        if (lane == 0) {
#pragma unroll
            for (int e = 0; e < 8; e++) logits[(size_t)t * 8 + e] = a[e];
            int e1 = 0; float b1 = a[0];
            for (int e = 1; e < 8; e++) if (a[e] > b1) { b1 = a[e]; e1 = e; }
            int e2 = -1; float b2 = -1e30f;
            for (int e = 0; e < 8; e++) if (e != e1 && a[e] > b2) { b2 = a[e]; e2 = e; }
            int p = atomicAdd(&counts[e1], 1);
            tlist[e1 * T_TOK + p] = t;
            sel[2 * t + 0] = (u32)e1 | ((u32)p << 3);
            p = atomicAdd(&counts[e2], 1);
            tlist[e2 * T_TOK + p] = t;
            sel[2 * t + 1] = (u32)e2 | ((u32)p << 3);
        }
        return;
    }

    // ---------------- weight transpose+convert into GEMM-ready B-images ----------------
    const float* src; u16* dst; int R, C, id;
    if (bid < RTR_BLK + TW_BLK) { id = bid - RTR_BLK;          src = w1; dst = w1s; R = HID;   C = INTER; }
    else                        { id = bid - RTR_BLK - TW_BLK; src = w2; dst = w2s; R = INTER; C = HID;   }
    const int cpb = C >> 6, rpb = R >> 6;
    const int bx = id % cpb;
    const int tmp = id / cpb;
    const int by = tmp % rpb;            // kstep
    const int e  = tmp / rpb;
    const int c0 = bx * 64, r0 = by * 64;
    const float* s = src + (size_t)e * R * C + (size_t)r0 * C + c0;
#pragma unroll
    for (int it = 0; it < 4; it++) {
        int idx = it * 256 + tid;       // 0..1023
        int r = idx >> 4;               // 0..63
        int c4 = (idx & 15) * 4;        // 0,4,...,60
        float4 v = *(const float4*)(s + (size_t)r * C + c4);
        tl[c4 + 0][r] = v.x;
        tl[c4 + 1][r] = v.y;
        tl[c4 + 2][r] = v.z;
        tl[c4 + 3][r] = v.w;
    }
    __syncthreads();
    // image base: (e, nt = c0>>7, kstep = by) + half-select (c0>>6)&1
    const int mbase = ((c0 >> 6) & 1) << 6;
    u16* img = dst + (((size_t)e * (C >> 7) + (size_t)(c0 >> 7)) * (size_t)(R >> 6) + by) * 8192
                   + (size_t)mbase * 64;
#pragma unroll
    for (int it = 0; it < 2; it++) {
        int idx = it * 256 + tid;       // 0..511
        int c = idx >> 3;               // 0..63 (local m)
        int sp = idx & 7;
        int m = mbase + c;              // image-global m for k-rotation
        int rg = ((sp - m) & 7) * 8;
        u32 o[4];
#pragma unroll
        for (int p = 0; p < 4; p++)
            o[p] = pk2bf(tl[c][rg + 2 * p], tl[c][rg + 2 * p + 1]);
        *(uint4*)(img + (size_t)c * 64 + sp * 8) = *(uint4*)o;
    }
}

// ---------------- GEMM1: h1 = gelu(x_gathered @ w1), bf16 MFMA ----------------
// (round-0 proven structure: 128x128 tile, 4 waves, 2 barriers/K-step, 4 blocks/CU)
// B-side now streams sequential 16 KB images.
__global__ __launch_bounds__(256, 1) void gemm1_kernel(
    const u16* __restrict__ xb, const u16* __restrict__ w1s,
    const int* __restrict__ counts, const int* __restrict__ tlist,
    u16* __restrict__ h1b)
{
    const int e = blockIdx.z, mt = blockIdx.y, nt = blockIdx.x;
    const int cnt = counts[e];
    if (mt * 128 >= cnt) return;
    __shared__ __align__(16) u16 As[8192];   // [m 0..127][k-chunk swizzled]
    __shared__ __align__(16) u16 Bs[8192];   // [n 0..127][k-chunk swizzled]
    __shared__ int toks[128];
    const int tid = threadIdx.x, lane = tid & 63, wv = tid >> 6;
    if (tid < 128) toks[tid] = tlist[e * T_TOK + min(mt * 128 + tid, cnt - 1)];
    __syncthreads();

    f32x4 acc[4][4] = {};
    const int wm = wv & 1, wn = wv >> 1;
    const int sj = tid >> 3, sp = tid & 7;

    size_t abase[4];
#pragma unroll
    for (int j = 0; j < 4; j++) {
        int m = j * 32 + sj;
        abase[j] = (size_t)toks[m] * HID + ((sp - m) & 7) * 8;
    }
    const u16* img1 = w1s + (size_t)(e * 32 + nt) * 16 * 8192 + (size_t)tid * 8;

    for (int h0 = 0; h0 < HID; h0 += 64) {
#pragma unroll
        for (int j = 0; j < 4; j++)
            gl2lds16(xb + abase[j] + h0, &As[j * 2048 + wv * 512]);
#pragma unroll
        for (int j = 0; j < 4; j++)
            gl2lds16(img1 + ((size_t)h0 << 7) + j * 2048, &Bs[j * 2048 + wv * 512]);
        __syncthreads();
#pragma unroll
        for (int kk = 0; kk < 2; kk++) {
            bf16x8 a[4], b[4];
            const int jjb = kk * 4 + (lane >> 4);
#pragma unroll
            for (int i = 0; i < 4; i++) {
                int m = wm * 64 + i * 16 + (lane & 15);
                a[i] = *(const bf16x8*)&As[m * 64 + ((jjb + m) & 7) * 8];
            }
#pragma unroll
            for (int i = 0; i < 4; i++) {
                int n = wn * 64 + i * 16 + (lane & 15);
                b[i] = *(const bf16x8*)&Bs[n * 64 + ((jjb + n) & 7) * 8];
            }
#pragma unroll
            for (int i = 0; i < 4; i++)
#pragma unroll
                for (int j = 0; j < 4; j++)
                    acc[i][j] = __builtin_amdgcn_mfma_f32_16x16x32_bf16(
                        a[i], b[j], acc[i][j], 0, 0, 0);
        }
        __syncthreads();
    }

    int prow = 0;
#pragma unroll
    for (int i = 0; i < 8; i++) prow += (i < e) ? counts[i] : 0;
    const int pb = prow + mt * 128;
    const bool full = (mt * 128 + 128 <= cnt);
#pragma unroll
    for (int i = 0; i < 4; i++) {
        const int mb = wm * 64 + i * 16 + ((lane >> 4) << 2);
#pragma unroll
        for (int j = 0; j < 4; j++) {
            const int n = nt * 128 + wn * 64 + j * 16 + (lane & 15);
#pragma unroll
            for (int r = 0; r < 4; r++) {
                const int m = mb + r;
                if (full || mt * 128 + m < cnt) {
                    h1b[(size_t)(pb + m) * INTER + n] = bfc(fast_gelu(acc[i][j][r]));
                }
            }
        }
    }
}

// -------- GEMM2: y_ks[row] = h1 @ w2 (per k-split), plain f32 stores, no atomics -----
// 1-D grid with XCD grouping: all 16 sharers (nt x ks) of one (e,mt) A-panel land on
// one XCD, contiguous in per-XCD dispatch order -> A-panel is L2-local.
// id = ((gx*16 + q) << 3) | gl ; g = gx*8+gl = e*16+mt ; q = nt + 8*ks
__global__ __launch_bounds__(256, 1) void gemm2_kernel(
    const u16* __restrict__ h1b, const u16* __restrict__ w2s,
    const int* __restrict__ counts, const int* __restrict__ tlist,
    float* __restrict__ y)
{
    const int id = blockIdx.x;
    const int gl = id & 7;
    const int rest = id >> 3;
    const int q  = rest & 15;
    const int gx = rest >> 4;
    const int g  = gx * 8 + gl;
    const int e  = g >> 4, mt = g & 15;
    const int nt = q & 7, ks = q >> 3;
    const int cnt = counts[e];
    if (mt * 128 >= cnt) return;
    __shared__ __align__(16) u16 As[8192];
    __shared__ __align__(16) u16 Bs[8192];
    const int tid = threadIdx.x, lane = tid & 63, wv = tid >> 6;

    int prow = 0;
#pragma unroll
    for (int i = 0; i < 8; i++) prow += (i < e) ? counts[i] : 0;

    f32x4 acc[4][4] = {};
    const int wm = wv & 1, wn = wv >> 1;
    const int sj = tid >> 3, sp = tid & 7;

    size_t abase[4];
#pragma unroll
    for (int j = 0; j < 4; j++) {
        int m = j * 32 + sj;
        int row = prow + min(mt * 128 + m, cnt - 1);
        abase[j] = (size_t)row * INTER + ((sp - m) & 7) * 8;
    }
    const u16* img2 = w2s + (size_t)(e * 8 + nt) * 64 * 8192 + (size_t)tid * 8;

    const int i_lo = ks * (INTER / 2), i_hi = i_lo + (INTER / 2);
    for (int i0 = i_lo; i0 < i_hi; i0 += 64) {
#pragma unroll
        for (int j = 0; j < 4; j++)
            gl2lds16(h1b + abase[j] + i0, &As[j * 2048 + wv * 512]);
#pragma unroll
        for (int j = 0; j < 4; j++)
            gl2lds16(img2 + ((size_t)i0 << 7) + j * 2048, &Bs[j * 2048 + wv * 512]);
        __syncthreads();
#pragma unroll
        for (int kk = 0; kk < 2; kk++) {
            bf16x8 a[4], b[4];
            const int jjb = kk * 4 + (lane >> 4);
#pragma unroll
            for (int i = 0; i < 4; i++) {
                int m = wm * 64 + i * 16 + (lane & 15);
                a[i] = *(const bf16x8*)&As[m * 64 + ((jjb + m) & 7) * 8];
            }
#pragma unroll
            for (int i = 0; i < 4; i++) {
                int n = wn * 64 + i * 16 + (lane & 15);
                b[i] = *(const bf16x8*)&Bs[n * 64 + ((jjb + n) & 7) * 8];
            }
#pragma unroll
            for (int i = 0; i < 4; i++)
#pragma unroll
                for (int j = 0; j < 4; j++)
                    acc[i][j] = __builtin_amdgcn_mfma_f32_16x16x32_bf16(
                        a[i], b[j], acc[i][j], 0, 0, 0);
        }
        __syncthreads();
    }

    float* yk = y + (size_t)ks * (8192ull * HID);
    const bool full = (mt * 128 + 128 <= cnt);
#pragma unroll
    for (int i = 0; i < 4; i++) {
        const int mb = wm * 64 + i * 16 + ((lane >> 4) << 2);
#pragma unroll
        for (int j = 0; j < 4; j++) {
            const int n = nt * 128 + wn * 64 + j * 16 + (lane & 15);
#pragma unroll
            for (int r = 0; r < 4; r++) {
                const int m = mb + r;
                if (full || mt * 128 + m < cnt) {
                    yk[(size_t)(prow + mt * 128 + m) * HID + n] = acc[i][j][r];
                }
            }
        }
    }
}

// -------- combine: out[t] = w0*(y0[g0]+y1[g0]) + w1*(y0[g1]+y1[g1]) --------
// one block per token; weights recomputed from logits (bit-identical to router math)
__global__ __launch_bounds__(256) void combine_kernel(
    const float* __restrict__ y, const u32* __restrict__ sel,
    const int* __restrict__ counts, const float* __restrict__ logits,
    float* __restrict__ out)
{
    const int t = blockIdx.x;
    const u32 s0 = sel[2 * t + 0], s1 = sel[2 * t + 1];
    const int e0 = s0 & 7, p0 = s0 >> 3;
    const int e1 = s1 & 7, p1 = s1 >> 3;
    int off0 = 0, off1 = 0;
#pragma unroll
    for (int i = 0; i < 8; i++) {
        int c = counts[i];
        off0 += (i < e0) ? c : 0;
        off1 += (i < e1) ? c : 0;
    }
    const size_t g0 = (size_t)(off0 + p0) * HID;
    const size_t g1 = (size_t)(off1 + p1) * HID;
    const float la = logits[(size_t)t * 8 + e0];   // primary (slot 0) logit
    const float lb = logits[(size_t)t * 8 + e1];
    const float w0 = 1.0f / (1.0f + expf(lb - la));
    const float w1 = 1.0f - w0;

    const int c = threadIdx.x * 4;
    const float* y1p = y + 8192ull * HID;
    f32x4 a0 = *(const f32x4*)(y + g0 + c);
    f32x4 a1 = *(const f32x4*)(y1p + g0 + c);
    f32x4 b0 = *(const f32x4*)(y + g1 + c);
    f32x4 b1 = *(const f32x4*)(y1p + g1 + c);
    f32x4 o = w0 * (a0 + a1) + w1 * (b0 + b1);
    *(f32x4*)(out + (size_t)t * HID + c) = o;
}

extern "C" void kernel_launch(void* const* d_in, const int* in_sizes, int n_in,
                              void* d_out, int out_size, void* d_ws, size_t ws_size,
                              hipStream_t stream)
{
    const float* x  = (const float*)d_in[0];   // [4,1024,1024]
    const float* gw = (const float*)d_in[1];   // [1024,8]
    const float* w1 = (const float*)d_in[2];   // [8,1024,4096]
    const float* w2 = (const float*)d_in[3];   // [8,4096,1024]
    float* out    = (float*)d_out;             // 4194304 out + 32768 logits
    float* logits = out + 4194304;

    char* ws = (char*)d_ws;
    int*   counts = (int*)ws;
    int*   tlist  = (int*)(ws + 1024);
    u32*   sel    = (u32*)(ws + 132096);
    u16*   xb     = (u16*)(ws + 263168);
    u16*   w1s    = (u16*)(ws + 8651776);
    float* y      = (float*)(ws + 8651776);     // aliases w1s (dead after gemm1)
    u16*   w2s    = (u16*)(ws + 75760640);
    u16*   h1b    = (u16*)(ws + 142869504);

    if (ws_size < WS_NEEDED) return;

    hipMemsetAsync(counts, 0, 256, stream);

    // fused: router + x->bf16 + w1/w2 -> GEMM-ready B-images
    preproc_kernel<<<RTR_BLK + 2 * TW_BLK, 256, 0, stream>>>(
        x, gw, w1, w2, logits, counts, tlist, sel, xb, w1s, w2s);

    // gemm1: grid x=nt(32), y=mt(16), z=e(8)
    gemm1_kernel<<<dim3(32, 16, 8), 256, 0, stream>>>(xb, w1s, counts, tlist, h1b);
    // gemm2: 1-D XCD-grouped grid (2048 blocks); writes y (w1s region now dead)
    gemm2_kernel<<<2048, 256, 0, stream>>>(h1b, w2s, counts, tlist, y);
    // combine: one block per token
    combine_kernel<<<T_TOK, 256, 0, stream>>>(y, sel, counts, logits, out);
}